// Round 5
// baseline (552.707 us; speedup 1.0000x reference)
//
#include <hip/hip_runtime.h>
#include <hip/hip_bf16.h>
#include <stdint.h>

// Problem constants
#define NTOK   64      // tokens per window
#define CDIM   256     // embed dim
#define NHEAD  8
#define DHEAD  32
#define NWIN   256     // windows per image (mask count)
#define BWIN   2048    // total windows
#define MROWS  131072  // BWIN*NTOK

typedef __attribute__((ext_vector_type(8))) short short8;
typedef __attribute__((ext_vector_type(4))) float f32x4;

__device__ __forceinline__ ushort f2bf(float f) {
  uint32_t u = __float_as_uint(f);
  u += 0x7fffu + ((u >> 16) & 1u);   // RNE
  return (ushort)(u >> 16);
}
__device__ __forceinline__ void unpack8(uint4 u, float* f) {
  f[0] = __uint_as_float(u.x << 16);
  f[1] = __uint_as_float(u.x & 0xffff0000u);
  f[2] = __uint_as_float(u.y << 16);
  f[3] = __uint_as_float(u.y & 0xffff0000u);
  f[4] = __uint_as_float(u.z << 16);
  f[5] = __uint_as_float(u.z & 0xffff0000u);
  f[6] = __uint_as_float(u.w << 16);
  f[7] = __uint_as_float(u.w & 0xffff0000u);
}

// ---------------- tiny prep kernels ----------------

__global__ void k_cast_bf16(const float* __restrict__ src, ushort* __restrict__ dst, int n4) {
  int i = blockIdx.x * blockDim.x + threadIdx.x;
  int stride = gridDim.x * blockDim.x;
  for (; i < n4; i += stride) {
    float4 v = ((const float4*)src)[i];
    ushort4 o;
    o.x = f2bf(v.x); o.y = f2bf(v.y); o.z = f2bf(v.z); o.w = f2bf(v.w);
    ((ushort4*)dst)[i] = o;
  }
}

// src[K][N] fp32 -> dst[N][K] bf16
__global__ void k_transpose_bf16(const float* __restrict__ src, ushort* __restrict__ dst, int K, int N) {
  int idx = blockIdx.x * 256 + threadIdx.x;
  if (idx < N * K) {
    int n = idx / K, k = idx - n * K;
    dst[idx] = f2bf(src[(size_t)k * N + n]);
  }
}

// CPB MLP: bias_table[225][8]
__global__ void k_cpb(const float* __restrict__ ct, const float* __restrict__ w1,
                      const float* __restrict__ b1, const float* __restrict__ w2,
                      float* __restrict__ out) {
  int p = blockIdx.x, t = threadIdx.x;
  float c0 = ct[p * 2], c1 = ct[p * 2 + 1];
  float acc[8];
#pragma unroll
  for (int h = 0; h < 8; ++h) acc[h] = 0.f;
  for (int j = t; j < 512; j += 256) {
    float hj = fmaxf(0.f, fmaf(c0, w1[j], fmaf(c1, w1[512 + j], b1[j])));
#pragma unroll
    for (int h = 0; h < 8; ++h) acc[h] = fmaf(hj, w2[j * 8 + h], acc[h]);
  }
#pragma unroll
  for (int off = 1; off < 64; off <<= 1)
#pragma unroll
    for (int h = 0; h < 8; ++h) acc[h] += __shfl_xor(acc[h], off, 64);
  __shared__ float red[4][8];
  if ((t & 63) == 0)
#pragma unroll
    for (int h = 0; h < 8; ++h) red[t >> 6][h] = acc[h];
  __syncthreads();
  if (t < 8) out[p * 8 + t] = red[0][t] + red[1][t] + red[2][t] + red[3][t];
}

// relbC for the SWAPPED (S^T) fragment order:
// idx = ((((h*4+nt)*4+mt)*4+g)*16+l16)*4+reg
// value = 16*sigmoid(bias_table[rpi[q*64+k]][h]), q = mt*16+l16, k = nt*16+g*4+reg
__global__ void k_relbC(const float* __restrict__ bt, const int* __restrict__ rpi,
                        float* __restrict__ out) {
  int idx = blockIdx.x * 256 + threadIdx.x;  // 32768 total
  int reg = idx & 3, l16 = (idx >> 2) & 15, g = (idx >> 6) & 3;
  int mt = (idx >> 8) & 3, nt = (idx >> 10) & 3, h = idx >> 12;
  int q = mt * 16 + l16, k = nt * 16 + g * 4 + reg;
  float v = bt[rpi[q * 64 + k] * 8 + h];
  out[idx] = 16.0f / (1.0f + __expf(-v));
}

// mask bits for the swapped order, packed for one-uint4-per-lane loads:
// out[wi*1024 + (g*16+l16)*16 + (nt*4+mt)] : bit reg = (mask[wi][q][k] == 0)
// with q = mt*16+l16, k = nt*16+g*4+reg.  (mask values are exactly 0 or -100)
__global__ void k_maskBits(const float* __restrict__ mask, unsigned char* __restrict__ out) {
  int idx = blockIdx.x * 256 + threadIdx.x;  // 262144 total
  int b = idx & 15;            // nt*4+mt
  int q6 = (idx >> 4) & 63;    // g*16+l16
  int wi = idx >> 10;
  int nt = b >> 2, mt = b & 3, g = q6 >> 4, l16 = q6 & 15;
  unsigned char v = 0;
#pragma unroll
  for (int reg = 0; reg < 4; ++reg) {
    int q = mt * 16 + l16, k = nt * 16 + g * 4 + reg;
    if (mask[(size_t)wi * 4096 + q * 64 + k] == 0.0f) v |= (unsigned char)(1 << reg);
  }
  out[idx] = v;
}

// ---------------- MFMA GEMM: C[M][N] = A[M][K] * BT[N][K]^T ----------------
template <int MODE>
__global__ __launch_bounds__(256, 2) void gemm_bt(const ushort* __restrict__ A,
                                                  const ushort* __restrict__ BT,
                                                  void* __restrict__ Cout,
                                                  const float* __restrict__ bias0,
                                                  const float* __restrict__ bias1,
                                                  int K, int N) {
  __shared__ ushort As[128 * 64];
  __shared__ ushort Bs[128 * 64];
  const int t = threadIdx.x;
  const int bn = blockIdx.x, bm = blockIdx.y;
  const int wv = t >> 6, lane = t & 63, quad = lane >> 4, l16 = lane & 15;
  const int mbase = (wv & 1) * 64, nbase = (wv >> 1) * 64;

  f32x4 acc[4][4] = {};

  const int nkt = K >> 6;
  for (int kt = 0; kt < nkt; ++kt) {
    __syncthreads();
#pragma unroll
    for (int i = 0; i < 4; ++i) {
      int idx = i * 256 + t;
      int m = idx >> 3, c = idx & 7;
      int sw = (m * 8 + (c ^ (m & 7))) * 8;
      *(uint4*)(As + sw) = *(const uint4*)(A + (size_t)(bm * 128 + m) * K + kt * 64 + c * 8);
      *(uint4*)(Bs + sw) = *(const uint4*)(BT + (size_t)(bn * 128 + m) * K + kt * 64 + c * 8);
    }
    __syncthreads();
#pragma unroll
    for (int k2 = 0; k2 < 2; ++k2) {
      const int cidx = (k2 * 4 + quad) ^ (l16 & 7);
      short8 a[4], b[4];
#pragma unroll
      for (int mt = 0; mt < 4; ++mt)
        a[mt] = *(const short8*)(As + ((mbase + mt * 16 + l16) * 8 + cidx) * 8);
#pragma unroll
      for (int nt = 0; nt < 4; ++nt)
        b[nt] = *(const short8*)(Bs + ((nbase + nt * 16 + l16) * 8 + cidx) * 8);
#pragma unroll
      for (int mt = 0; mt < 4; ++mt)
#pragma unroll
        for (int nt = 0; nt < 4; ++nt)
          acc[mt][nt] = __builtin_amdgcn_mfma_f32_16x16x32_bf16(a[mt], b[nt], acc[mt][nt], 0, 0, 0);
    }
  }

#pragma unroll
  for (int mt = 0; mt < 4; ++mt)
#pragma unroll
    for (int nt = 0; nt < 4; ++nt) {
      int j = bn * 128 + nbase + nt * 16 + l16;
      int gm = bm * 128 + mbase + mt * 16 + quad * 4;
      float bs;
      if (MODE == 0) bs = (j < 256) ? bias0[j] : ((j < 512) ? 0.0f : bias1[j - 512]);
      else bs = bias0[j];
#pragma unroll
      for (int i2 = 0; i2 < 4; ++i2) {
        float v = acc[mt][nt][i2] + bs;
        size_t off = (size_t)(gm + i2) * N + j;
        if (MODE == 0) ((ushort*)Cout)[off] = f2bf(v);
        else ((float*)Cout)[off] = v;
      }
    }
}

// ---------------- MFMA attention (swapped S^T, per-mt-tile pipeline) ----------------
// 1 block / window, 4 fully-independent waves (wave wv owns head pass*4+wv);
// no __syncthreads (all LDS per-wave private; DS pipe in-order within a wave).
// Per q-tile mt: 4 S^T-mfma -> bias/mask -> in-lane softmax (2 shfl) ->
// pack P -> Ps[16-row tile, reused per mt] -> 4 PV-mfma -> store O.
// Peak liveness: kfr(16)+vf(16)+per-mt temps(~50) -> fits (256,3) cap 170.
// LDS 27648 B/block; occupancy register-limited at 3 blocks/CU (12 waves).
__global__ __launch_bounds__(256, 3) void k_attn_mfma(const ushort* __restrict__ qkv,
                                                      const unsigned char* __restrict__ maskN,
                                                      const float* __restrict__ ls,
                                                      const float* __restrict__ relbC,
                                                      ushort* __restrict__ aob) {
  __shared__ ushort Vt[4][32][72];   // V^T per wave: [dim][tok]
  __shared__ ushort Ps[4][16][72];   // one 16-q-row P tile per wave, reused per mt
  const int b = blockIdx.x, t = threadIdx.x;
  const int wi = b & (NWIN - 1);
  const int wv = t >> 6, lane = t & 63;
  const int g = lane >> 4, l16 = lane & 15;
  const size_t rowb = (size_t)b * 64;

  // ---- mask bits for this (window, lane): 16 nibbles, one per (nt,mt) ----
  const uint4 mbits = *(const uint4*)(maskN + (size_t)wi * 1024 + (g * 16 + l16) * 16);
  const unsigned char* mb = (const unsigned char*)&mbits;

  for (int pass = 0; pass < 2; ++pass) {
    const int h = pass * 4 + wv;

    // ---- V -> Vt[wv] (transposed; per-wave private) ----
    {
      const int tok = lane;
      const size_t base = (rowb + tok) * 768 + 512 + h * 32;
      union { uint4 u[4]; ushort s[32]; } raw;
      raw.u[0] = *(const uint4*)(qkv + base);
      raw.u[1] = *(const uint4*)(qkv + base + 8);
      raw.u[2] = *(const uint4*)(qkv + base + 16);
      raw.u[3] = *(const uint4*)(qkv + base + 24);
#pragma unroll
      for (int d = 0; d < 32; ++d) Vt[wv][d][tok] = raw.s[d];
    }

    // ---- K fragments: direct global load + in-register norm ----
    const float sc = __expf(fminf(ls[h], 4.6051701859880914f));
    short8 kfr[4];
#pragma unroll
    for (int nt = 0; nt < 4; ++nt) {
      uint4 r = *(const uint4*)(qkv + (rowb + nt * 16 + l16) * 768 + 256 + h * 32 + g * 8);
      float f[8];
      unpack8(r, f);
      float s = 0.f;
#pragma unroll
      for (int j = 0; j < 8; ++j) s = fmaf(f[j], f[j], s);
      s += __shfl_xor(s, 16, 64);
      s += __shfl_xor(s, 32, 64);
      const float fac = 1.0f / fmaxf(sqrtf(s), 1e-12f);
      union { short8 v; ushort us[8]; } o;
#pragma unroll
      for (int j = 0; j < 8; ++j) o.us[j] = f2bf(f[j] * fac);
      kfr[nt] = o.v;
    }

    // ---- V B-fragments (after Vt writes; same-wave in-order DS) ----
    short8 vf[2][2];
#pragma unroll
    for (int kt = 0; kt < 2; ++kt)
#pragma unroll
      for (int n2 = 0; n2 < 2; ++n2)
        vf[kt][n2] = *(const short8*)&Vt[wv][n2 * 16 + l16][kt * 32 + g * 8];

    const f32x4 zero = {0.f, 0.f, 0.f, 0.f};

    // ---- per q-tile pipeline ----
#pragma unroll
    for (int mt = 0; mt < 4; ++mt) {
      // Q fragment for this tile: load + norm (+ logit scale)
      short8 qfr;
      {
        uint4 r = *(const uint4*)(qkv + (rowb + mt * 16 + l16) * 768 + h * 32 + g * 8);
        float f[8];
        unpack8(r, f);
        float s = 0.f;
#pragma unroll
        for (int j = 0; j < 8; ++j) s = fmaf(f[j], f[j], s);
        s += __shfl_xor(s, 16, 64);
        s += __shfl_xor(s, 32, 64);
        const float fac = sc / fmaxf(sqrtf(s), 1e-12f);
        union { short8 v; ushort us[8]; } o;
#pragma unroll
        for (int j = 0; j < 8; ++j) o.us[j] = f2bf(f[j] * fac);
        qfr = o.v;
      }

      // S^T column: sv[nt][reg] = S[q=mt*16+l16][k=nt*16+g*4+reg]
      f32x4 sv[4];
#pragma unroll
      for (int nt = 0; nt < 4; ++nt)
        sv[nt] = __builtin_amdgcn_mfma_f32_16x16x32_bf16(kfr[nt], qfr, zero, 0, 0, 0);

      // + relb + mask
#pragma unroll
      for (int nt = 0; nt < 4; ++nt) {
        float4 rb = *(const float4*)(relbC + (size_t)(((h * 4 + nt) * 4 + mt) * 4 + g) * 64 + l16 * 4);
        const unsigned char nb = mb[nt * 4 + mt];
        sv[nt][0] += rb.x + ((nb & 1) ? 0.f : -100.f);
        sv[nt][1] += rb.y + ((nb & 2) ? 0.f : -100.f);
        sv[nt][2] += rb.z + ((nb & 4) ? 0.f : -100.f);
        sv[nt][3] += rb.w + ((nb & 8) ? 0.f : -100.f);
      }

      // softmax for these 16 q-rows (16 in-lane values + 2 shfl each phase)
      float m = sv[0][0];
#pragma unroll
      for (int nt = 0; nt < 4; ++nt)
#pragma unroll
        for (int reg = 0; reg < 4; ++reg) m = fmaxf(m, sv[nt][reg]);
      m = fmaxf(m, __shfl_xor(m, 16, 64));
      m = fmaxf(m, __shfl_xor(m, 32, 64));
      float s = 0.f;
#pragma unroll
      for (int nt = 0; nt < 4; ++nt)
#pragma unroll
        for (int reg = 0; reg < 4; ++reg) {
          float e = __expf(sv[nt][reg] - m);
          sv[nt][reg] = e;
          s += e;
        }
      s += __shfl_xor(s, 16, 64);
      s += __shfl_xor(s, 32, 64);
      const float iv = 1.0f / s;

      // pack (1/sum folded) -> Ps tile (reused each mt; same-wave in-order DS)
#pragma unroll
      for (int nt = 0; nt < 4; ++nt) {
        uint2 u;
        u.x = (uint32_t)f2bf(sv[nt][0] * iv) | ((uint32_t)f2bf(sv[nt][1] * iv) << 16);
        u.y = (uint32_t)f2bf(sv[nt][2] * iv) | ((uint32_t)f2bf(sv[nt][3] * iv) << 16);
        *(uint2*)&Ps[wv][l16][nt * 16 + g * 4] = u;
      }

      // PV for this tile; store O immediately (rows pre-normalized via P)
      {
        short8 pf0 = *(const short8*)&Ps[wv][l16][g * 8];
        short8 pf1 = *(const short8*)&Ps[wv][l16][32 + g * 8];
        f32x4 ovA = __builtin_amdgcn_mfma_f32_16x16x32_bf16(pf0, vf[0][0], zero, 0, 0, 0);
        f32x4 ovB = __builtin_amdgcn_mfma_f32_16x16x32_bf16(pf0, vf[0][1], zero, 0, 0, 0);
        ovA = __builtin_amdgcn_mfma_f32_16x16x32_bf16(pf1, vf[1][0], ovA, 0, 0, 0);
        ovB = __builtin_amdgcn_mfma_f32_16x16x32_bf16(pf1, vf[1][1], ovB, 0, 0, 0);
#pragma unroll
        for (int reg = 0; reg < 4; ++reg) {
          int r = mt * 16 + g * 4 + reg;
          aob[(rowb + r) * 256 + h * 32 + l16] = f2bf(ovA[reg]);
          aob[(rowb + r) * 256 + h * 32 + 16 + l16] = f2bf(ovB[reg]);
        }
      }
    }
  }
}

// ---------------- launch ----------------

extern "C" void kernel_launch(void* const* d_in, const int* in_sizes, int n_in,
                              void* d_out, int out_size, void* d_ws, size_t ws_size,
                              hipStream_t stream) {
  const float* x      = (const float*)d_in[0];
  const float* mask   = (const float*)d_in[1];
  const float* qkv_w  = (const float*)d_in[2];
  const float* q_bias = (const float*)d_in[3];
  const float* v_bias = (const float*)d_in[4];
  const float* lscale = (const float*)d_in[5];
  const float* ctbl   = (const float*)d_in[6];
  const float* m1w    = (const float*)d_in[7];
  const float* m1b    = (const float*)d_in[8];
  const float* m2w    = (const float*)d_in[9];
  const float* projw  = (const float*)d_in[10];
  const float* projb  = (const float*)d_in[11];
  const int*   rpi    = (const int*)d_in[12];

  char* w = (char*)d_ws;
  float*  bias_table = (float*)(w + 0);               //    7200 B
  float*  relbC      = (float*)(w + 8192);            //  131072 B
  unsigned char* maskN = (unsigned char*)(w + 139264); //  262144 B
  ushort* qkvWT      = (ushort*)(w + 4333568);        //  393216 B  [768][256] bf16
  ushort* projWT     = (ushort*)(w + 4726784);        //  131072 B  [256][256] bf16
  ushort* xb         = (ushort*)(w + 4857856);        // 67108864 B [131072][256] bf16
  ushort* qkvb       = (ushort*)(w + 71966720ull);    // 201326592 B [131072][768] bf16
  ushort* aob        = (ushort*)(w + 273293312ull);   // 67108864 B [131072][256] bf16
  (void)ws_size; (void)n_in; (void)in_sizes; (void)out_size;

  k_cast_bf16<<<4096, 256, 0, stream>>>(x, xb, MROWS * CDIM / 4);
  k_transpose_bf16<<<768, 256, 0, stream>>>(qkv_w, qkvWT, 256, 768);
  k_transpose_bf16<<<256, 256, 0, stream>>>(projw, projWT, 256, 256);
  k_cpb<<<225, 256, 0, stream>>>(ctbl, m1w, m1b, m2w, bias_table);
  k_relbC<<<128, 256, 0, stream>>>(bias_table, rpi, relbC);
  k_maskBits<<<1024, 256, 0, stream>>>(mask, maskN);

  gemm_bt<0><<<dim3(6, 1024), 256, 0, stream>>>(xb, qkvWT, qkvb, q_bias, v_bias, 256, 768);
  k_attn_mfma<<<BWIN, 256, 0, stream>>>(qkvb, maskN, lscale, relbC, aob);
  gemm_bt<1><<<dim3(2, 1024), 256, 0, stream>>>(aob, projWT, d_out, projb, nullptr, 256, 256);
}

// Round 7
// 547.108 us; speedup vs baseline: 1.0102x; 1.0102x over previous
//
#include <hip/hip_runtime.h>
#include <hip/hip_bf16.h>
#include <stdint.h>

// Problem constants
#define NTOK   64      // tokens per window
#define CDIM   256     // embed dim
#define NHEAD  8
#define DHEAD  32
#define NWIN   256     // windows per image (mask count)
#define BWIN   2048    // total windows
#define MROWS  131072  // BWIN*NTOK

typedef __attribute__((ext_vector_type(8))) short short8;
typedef __attribute__((ext_vector_type(4))) float f32x4;

__device__ __forceinline__ ushort f2bf(float f) {
  uint32_t u = __float_as_uint(f);
  u += 0x7fffu + ((u >> 16) & 1u);   // RNE
  return (ushort)(u >> 16);
}

// ---------------- tiny prep kernels ----------------

__global__ void k_cast_bf16(const float* __restrict__ src, ushort* __restrict__ dst, int n4) {
  int i = blockIdx.x * blockDim.x + threadIdx.x;
  int stride = gridDim.x * blockDim.x;
  for (; i < n4; i += stride) {
    float4 v = ((const float4*)src)[i];
    ushort4 o;
    o.x = f2bf(v.x); o.y = f2bf(v.y); o.z = f2bf(v.z); o.w = f2bf(v.w);
    ((ushort4*)dst)[i] = o;
  }
}

// src[K][N] fp32 -> dst[N][K] bf16
__global__ void k_transpose_bf16(const float* __restrict__ src, ushort* __restrict__ dst, int K, int N) {
  int idx = blockIdx.x * 256 + threadIdx.x;
  if (idx < N * K) {
    int n = idx / K, k = idx - n * K;
    dst[idx] = f2bf(src[(size_t)k * N + n]);
  }
}

// CPB MLP: bias_table[225][8]
__global__ void k_cpb(const float* __restrict__ ct, const float* __restrict__ w1,
                      const float* __restrict__ b1, const float* __restrict__ w2,
                      float* __restrict__ out) {
  int p = blockIdx.x, t = threadIdx.x;
  float c0 = ct[p * 2], c1 = ct[p * 2 + 1];
  float acc[8];
#pragma unroll
  for (int h = 0; h < 8; ++h) acc[h] = 0.f;
  for (int j = t; j < 512; j += 256) {
    float hj = fmaxf(0.f, fmaf(c0, w1[j], fmaf(c1, w1[512 + j], b1[j])));
#pragma unroll
    for (int h = 0; h < 8; ++h) acc[h] = fmaf(hj, w2[j * 8 + h], acc[h]);
  }
#pragma unroll
  for (int off = 1; off < 64; off <<= 1)
#pragma unroll
    for (int h = 0; h < 8; ++h) acc[h] += __shfl_xor(acc[h], off, 64);
  __shared__ float red[4][8];
  if ((t & 63) == 0)
#pragma unroll
    for (int h = 0; h < 8; ++h) red[t >> 6][h] = acc[h];
  __syncthreads();
  if (t < 8) out[p * 8 + t] = red[0][t] + red[1][t] + red[2][t] + red[3][t];
}

// relbC for the SWAPPED (S^T) fragment order:
// idx = ((((h*4+nt)*4+mt)*4+g)*16+l16)*4+reg
// value = 16*sigmoid(bias_table[rpi[q*64+k]][h]), q = mt*16+l16, k = nt*16+g*4+reg
__global__ void k_relbC(const float* __restrict__ bt, const int* __restrict__ rpi,
                        float* __restrict__ out) {
  int idx = blockIdx.x * 256 + threadIdx.x;  // 32768 total
  int reg = idx & 3, l16 = (idx >> 2) & 15, g = (idx >> 6) & 3;
  int mt = (idx >> 8) & 3, nt = (idx >> 10) & 3, h = idx >> 12;
  int q = mt * 16 + l16, k = nt * 16 + g * 4 + reg;
  float v = bt[rpi[q * 64 + k] * 8 + h];
  out[idx] = 16.0f / (1.0f + __expf(-v));
}

// mask bits for the swapped order, packed for one-uint4-per-lane loads:
// out[wi*1024 + (g*16+l16)*16 + (nt*4+mt)] : bit reg = (mask[wi][q][k] == 0)
// with q = mt*16+l16, k = nt*16+g*4+reg.  (mask values are exactly 0 or -100)
__global__ void k_maskBits(const float* __restrict__ mask, unsigned char* __restrict__ out) {
  int idx = blockIdx.x * 256 + threadIdx.x;  // 262144 total
  int b = idx & 15;            // nt*4+mt
  int q6 = (idx >> 4) & 63;    // g*16+l16
  int wi = idx >> 10;
  int nt = b >> 2, mt = b & 3, g = q6 >> 4, l16 = q6 & 15;
  unsigned char v = 0;
#pragma unroll
  for (int reg = 0; reg < 4; ++reg) {
    int q = mt * 16 + l16, k = nt * 16 + g * 4 + reg;
    if (mask[(size_t)wi * 4096 + q * 64 + k] == 0.0f) v |= (unsigned char)(1 << reg);
  }
  out[idx] = v;
}

// ---------------- MFMA GEMM: C[M][N] = A[M][K] * BT[N][K]^T ----------------
// MODE 0 (qkv): fused epilogue does qkv-bias add + per-head cosine L2-norm of
// Q and K + Q logit-scale, all in fp32 acc before the bf16 store. A head's 32
// cols live in 2 nt-registers x 16 l16-lanes of one wave -> sum-of-squares is
// 2 local fma + 4 shfl_xor. Block col-range decides category: bn<2 Q, bn<4 K,
// else V. This removes the entire norm pipeline (half the VALU + the register
// fat) from the attention kernel.
// MODE 1 (proj): bias add, fp32 store.
template <int MODE>
__global__ __launch_bounds__(256, 2) void gemm_bt(const ushort* __restrict__ A,
                                                  const ushort* __restrict__ BT,
                                                  void* __restrict__ Cout,
                                                  const float* __restrict__ bias0,
                                                  const float* __restrict__ bias1,
                                                  const float* __restrict__ lsc,
                                                  int K, int N) {
  __shared__ ushort As[128 * 64];
  __shared__ ushort Bs[128 * 64];
  const int t = threadIdx.x;
  const int bn = blockIdx.x, bm = blockIdx.y;
  const int wv = t >> 6, lane = t & 63, quad = lane >> 4, l16 = lane & 15;
  const int mbase = (wv & 1) * 64, nbase = (wv >> 1) * 64;

  f32x4 acc[4][4] = {};

  const int nkt = K >> 6;
  for (int kt = 0; kt < nkt; ++kt) {
    __syncthreads();
#pragma unroll
    for (int i = 0; i < 4; ++i) {
      int idx = i * 256 + t;
      int m = idx >> 3, c = idx & 7;
      int sw = (m * 8 + (c ^ (m & 7))) * 8;
      *(uint4*)(As + sw) = *(const uint4*)(A + (size_t)(bm * 128 + m) * K + kt * 64 + c * 8);
      *(uint4*)(Bs + sw) = *(const uint4*)(BT + (size_t)(bn * 128 + m) * K + kt * 64 + c * 8);
    }
    __syncthreads();
#pragma unroll
    for (int k2 = 0; k2 < 2; ++k2) {
      const int cidx = (k2 * 4 + quad) ^ (l16 & 7);
      short8 a[4], b[4];
#pragma unroll
      for (int mt = 0; mt < 4; ++mt)
        a[mt] = *(const short8*)(As + ((mbase + mt * 16 + l16) * 8 + cidx) * 8);
#pragma unroll
      for (int nt = 0; nt < 4; ++nt)
        b[nt] = *(const short8*)(Bs + ((nbase + nt * 16 + l16) * 8 + cidx) * 8);
#pragma unroll
      for (int mt = 0; mt < 4; ++mt)
#pragma unroll
        for (int nt = 0; nt < 4; ++nt)
          acc[mt][nt] = __builtin_amdgcn_mfma_f32_16x16x32_bf16(a[mt], b[nt], acc[mt][nt], 0, 0, 0);
    }
  }

  if (MODE == 0) {
    // category uniform per block: bn 0-1 -> Q (norm+scale), 2-3 -> K (norm), 4-5 -> V
    const int cat = bn >> 1;
#pragma unroll
    for (int a = 0; a < 2; ++a) {
      const int j0 = bn * 128 + nbase + a * 32 + l16;  // col of nt=2a element
      const int j1 = j0 + 16;                          // col of nt=2a+1 element
      float b0, b1;
      if (cat == 0)      { b0 = bias0[j0];       b1 = bias0[j1]; }
      else if (cat == 1) { b0 = 0.f;             b1 = 0.f; }
      else               { b0 = bias1[j0 - 512]; b1 = bias1[j1 - 512]; }
      float schead = 1.0f;
      if (cat == 0)
        schead = __expf(fminf(lsc[bn * 4 + (wv >> 1) * 2 + a], 4.6051701859880914f));
#pragma unroll
      for (int mt = 0; mt < 4; ++mt) {
        const int gm = bm * 128 + mbase + mt * 16 + quad * 4;
#pragma unroll
        for (int i2 = 0; i2 < 4; ++i2) {
          float v0 = acc[mt][2 * a][i2] + b0;
          float v1 = acc[mt][2 * a + 1][i2] + b1;
          float fac = 1.0f;
          if (cat < 2) {
            float s = fmaf(v0, v0, v1 * v1);
            s += __shfl_xor(s, 1, 64);
            s += __shfl_xor(s, 2, 64);
            s += __shfl_xor(s, 4, 64);
            s += __shfl_xor(s, 8, 64);
            fac = schead / fmaxf(sqrtf(s), 1e-12f);
          }
          size_t off = (size_t)(gm + i2) * N + j0;
          ((ushort*)Cout)[off]      = f2bf(v0 * fac);
          ((ushort*)Cout)[off + 16] = f2bf(v1 * fac);
        }
      }
    }
  } else {
#pragma unroll
    for (int mt = 0; mt < 4; ++mt)
#pragma unroll
      for (int nt = 0; nt < 4; ++nt) {
        int j = bn * 128 + nbase + nt * 16 + l16;
        int gm = bm * 128 + mbase + mt * 16 + quad * 4;
        float bs = bias0[j];
#pragma unroll
        for (int i2 = 0; i2 < 4; ++i2) {
          float v = acc[mt][nt][i2] + bs;
          ((float*)Cout)[(size_t)(gm + i2) * N + j] = v;
        }
      }
  }
}

// ---------------- MFMA attention (swapped S^T; Q/K pre-normalized) ----------------
// Q and K in qkvb are already cosine-normalized (+ Q logit-scaled) by gemm_bt<0>'s
// epilogue, so fragments are DIRECT short8 loads - no unpack/sqrt/pack pipeline.
// 1 block / window, 4 fully-independent waves (wave wv owns head pass*4+wv);
// no __syncthreads (all LDS per-wave private; DS pipe in-order within a wave).
// Per q-tile mt: 4 S^T-mfma -> bias/mask -> in-lane softmax (2 shfl) ->
// pack P (1/sum folded) -> Ps tile -> 4 PV-mfma -> store O.
// Peak liveness now ~kfr(16)+vf(16)+sv(16)+temps -> fits (256,3) cap 170
// without spill (gate: WRITE_SIZE must stay ~66MB). 3 blocks/CU, LDS 27648B.
__global__ __launch_bounds__(256, 3) void k_attn_mfma(const ushort* __restrict__ qkv,
                                                      const unsigned char* __restrict__ maskN,
                                                      const float* __restrict__ relbC,
                                                      ushort* __restrict__ aob) {
  __shared__ ushort Vt[4][32][72];   // V^T per wave: [dim][tok]
  __shared__ ushort Ps[4][16][72];   // one 16-q-row P tile per wave, reused per mt
  const int b = blockIdx.x, t = threadIdx.x;
  const int wi = b & (NWIN - 1);
  const int wv = t >> 6, lane = t & 63;
  const int g = lane >> 4, l16 = lane & 15;
  const size_t rowb = (size_t)b * 64;

  // ---- mask bits for this (window, lane): 16 nibbles, one per (nt,mt) ----
  const uint4 mbits = *(const uint4*)(maskN + (size_t)wi * 1024 + (g * 16 + l16) * 16);
  const unsigned char* mb = (const unsigned char*)&mbits;

  for (int pass = 0; pass < 2; ++pass) {
    const int h = pass * 4 + wv;

    // ---- V -> Vt[wv] (transposed; per-wave private) ----
    {
      const int tok = lane;
      const size_t base = (rowb + tok) * 768 + 512 + h * 32;
      union { uint4 u[4]; ushort s[32]; } raw;
      raw.u[0] = *(const uint4*)(qkv + base);
      raw.u[1] = *(const uint4*)(qkv + base + 8);
      raw.u[2] = *(const uint4*)(qkv + base + 16);
      raw.u[3] = *(const uint4*)(qkv + base + 24);
#pragma unroll
      for (int d = 0; d < 32; ++d) Vt[wv][d][tok] = raw.s[d];
    }

    // ---- K fragments: direct loads (pre-normalized bf16) ----
    short8 kfr[4];
#pragma unroll
    for (int nt = 0; nt < 4; ++nt)
      kfr[nt] = *(const short8*)(qkv + (rowb + nt * 16 + l16) * 768 + 256 + h * 32 + g * 8);

    // ---- V B-fragments (after Vt writes; same-wave in-order DS) ----
    short8 vf[2][2];
#pragma unroll
    for (int kt = 0; kt < 2; ++kt)
#pragma unroll
      for (int n2 = 0; n2 < 2; ++n2)
        vf[kt][n2] = *(const short8*)&Vt[wv][n2 * 16 + l16][kt * 32 + g * 8];

    const f32x4 zero = {0.f, 0.f, 0.f, 0.f};

    // ---- per q-tile pipeline ----
#pragma unroll
    for (int mt = 0; mt < 4; ++mt) {
      // Q fragment: direct load (pre-normalized + logit-scaled bf16)
      short8 qfr = *(const short8*)(qkv + (rowb + mt * 16 + l16) * 768 + h * 32 + g * 8);

      // S^T column: sv[nt][reg] = S[q=mt*16+l16][k=nt*16+g*4+reg]
      f32x4 sv[4];
#pragma unroll
      for (int nt = 0; nt < 4; ++nt)
        sv[nt] = __builtin_amdgcn_mfma_f32_16x16x32_bf16(kfr[nt], qfr, zero, 0, 0, 0);

      // + relb + mask
#pragma unroll
      for (int nt = 0; nt < 4; ++nt) {
        float4 rb = *(const float4*)(relbC + (size_t)(((h * 4 + nt) * 4 + mt) * 4 + g) * 64 + l16 * 4);
        const unsigned char nb = mb[nt * 4 + mt];
        sv[nt][0] += rb.x + ((nb & 1) ? 0.f : -100.f);
        sv[nt][1] += rb.y + ((nb & 2) ? 0.f : -100.f);
        sv[nt][2] += rb.z + ((nb & 4) ? 0.f : -100.f);
        sv[nt][3] += rb.w + ((nb & 8) ? 0.f : -100.f);
      }

      // softmax for these 16 q-rows (16 in-lane values + 2 shfl per phase)
      float m = sv[0][0];
#pragma unroll
      for (int nt = 0; nt < 4; ++nt)
#pragma unroll
        for (int reg = 0; reg < 4; ++reg) m = fmaxf(m, sv[nt][reg]);
      m = fmaxf(m, __shfl_xor(m, 16, 64));
      m = fmaxf(m, __shfl_xor(m, 32, 64));
      float s = 0.f;
#pragma unroll
      for (int nt = 0; nt < 4; ++nt)
#pragma unroll
        for (int reg = 0; reg < 4; ++reg) {
          float e = __expf(sv[nt][reg] - m);
          sv[nt][reg] = e;
          s += e;
        }
      s += __shfl_xor(s, 16, 64);
      s += __shfl_xor(s, 32, 64);
      const float iv = 1.0f / s;

      // pack (1/sum folded) -> Ps tile (reused each mt; same-wave in-order DS)
#pragma unroll
      for (int nt = 0; nt < 4; ++nt) {
        uint2 u;
        u.x = (uint32_t)f2bf(sv[nt][0] * iv) | ((uint32_t)f2bf(sv[nt][1] * iv) << 16);
        u.y = (uint32_t)f2bf(sv[nt][2] * iv) | ((uint32_t)f2bf(sv[nt][3] * iv) << 16);
        *(uint2*)&Ps[wv][l16][nt * 16 + g * 4] = u;
      }

      // PV for this tile; store O immediately (rows pre-normalized via P)
      {
        short8 pf0 = *(const short8*)&Ps[wv][l16][g * 8];
        short8 pf1 = *(const short8*)&Ps[wv][l16][32 + g * 8];
        f32x4 ovA = __builtin_amdgcn_mfma_f32_16x16x32_bf16(pf0, vf[0][0], zero, 0, 0, 0);
        f32x4 ovB = __builtin_amdgcn_mfma_f32_16x16x32_bf16(pf0, vf[0][1], zero, 0, 0, 0);
        ovA = __builtin_amdgcn_mfma_f32_16x16x32_bf16(pf1, vf[1][0], ovA, 0, 0, 0);
        ovB = __builtin_amdgcn_mfma_f32_16x16x32_bf16(pf1, vf[1][1], ovB, 0, 0, 0);
#pragma unroll
        for (int reg = 0; reg < 4; ++reg) {
          int r = mt * 16 + g * 4 + reg;
          aob[(rowb + r) * 256 + h * 32 + l16] = f2bf(ovA[reg]);
          aob[(rowb + r) * 256 + h * 32 + 16 + l16] = f2bf(ovB[reg]);
        }
      }
    }
  }
}

// ---------------- launch ----------------

extern "C" void kernel_launch(void* const* d_in, const int* in_sizes, int n_in,
                              void* d_out, int out_size, void* d_ws, size_t ws_size,
                              hipStream_t stream) {
  const float* x      = (const float*)d_in[0];
  const float* mask   = (const float*)d_in[1];
  const float* qkv_w  = (const float*)d_in[2];
  const float* q_bias = (const float*)d_in[3];
  const float* v_bias = (const float*)d_in[4];
  const float* lscale = (const float*)d_in[5];
  const float* ctbl   = (const float*)d_in[6];
  const float* m1w    = (const float*)d_in[7];
  const float* m1b    = (const float*)d_in[8];
  const float* m2w    = (const float*)d_in[9];
  const float* projw  = (const float*)d_in[10];
  const float* projb  = (const float*)d_in[11];
  const int*   rpi    = (const int*)d_in[12];

  char* w = (char*)d_ws;
  float*  bias_table = (float*)(w + 0);               //    7200 B
  float*  relbC      = (float*)(w + 8192);            //  131072 B
  unsigned char* maskN = (unsigned char*)(w + 139264); //  262144 B
  ushort* qkvWT      = (ushort*)(w + 4333568);        //  393216 B  [768][256] bf16
  ushort* projWT     = (ushort*)(w + 4726784);        //  131072 B  [256][256] bf16
  ushort* xb         = (ushort*)(w + 4857856);        // 67108864 B [131072][256] bf16
  ushort* qkvb       = (ushort*)(w + 71966720ull);    // 201326592 B [131072][768] bf16
  ushort* aob        = (ushort*)(w + 273293312ull);   // 67108864 B [131072][256] bf16
  (void)ws_size; (void)n_in; (void)in_sizes; (void)out_size;

  k_cast_bf16<<<4096, 256, 0, stream>>>(x, xb, MROWS * CDIM / 4);
  k_transpose_bf16<<<768, 256, 0, stream>>>(qkv_w, qkvWT, 256, 768);
  k_transpose_bf16<<<256, 256, 0, stream>>>(projw, projWT, 256, 256);
  k_cpb<<<225, 256, 0, stream>>>(ctbl, m1w, m1b, m2w, bias_table);
  k_relbC<<<128, 256, 0, stream>>>(bias_table, rpi, relbC);
  k_maskBits<<<1024, 256, 0, stream>>>(mask, maskN);

  gemm_bt<0><<<dim3(6, 1024), 256, 0, stream>>>(xb, qkvWT, qkvb, q_bias, v_bias, lscale, 256, 768);
  k_attn_mfma<<<BWIN, 256, 0, stream>>>(qkvb, maskN, relbC, aob);
  gemm_bt<1><<<dim3(2, 1024), 256, 0, stream>>>(aob, projWT, d_out, projb, nullptr, nullptr, 256, 256);
}